// Round 3
// baseline (126.044 us; speedup 1.0000x reference)
//
#include <hip/hip_runtime.h>

#define B 2
#define N 64
#define D 256
#define H 8
#define DK 32
#define M (B * N * N) // 8192

typedef __attribute__((ext_vector_type(8))) short bf16x8;
typedef __attribute__((ext_vector_type(4))) float f32x4;
typedef __attribute__((ext_vector_type(2))) float f32x2;

// P is head-major: 4 proj planes of [b][h][r1*64+r2][32] bf16
#define PROJ_ELEMS (2097152)  // B*H*4096*32

__device__ __forceinline__ ushort f2b(float f) {
    union { float f; unsigned u; } v; v.f = f;
    unsigned r = v.u + 0x7fffu + ((v.u >> 16) & 1u); // RNE
    return (ushort)(r >> 16);
}
__device__ __forceinline__ float b2f(ushort u) {
    union { unsigned u; float f; } v; v.u = ((unsigned)u) << 16; return v.f;
}
// unpack 2 packed bf16 (u32) -> float2
__device__ __forceinline__ f32x2 up2(unsigned u) {
    union { unsigned u; float f; } lo, hi;
    lo.u = u << 16; hi.u = u & 0xffff0000u;
    f32x2 r; r.x = lo.f; r.y = hi.f; return r;
}

// async 16B/lane global->LDS (dst = wave-uniform base + lane*16)
__device__ __forceinline__ void glds16(const ushort* g, ushort* l) {
    __builtin_amdgcn_global_load_lds(
        (const __attribute__((address_space(1))) unsigned int*)g,
        (__attribute__((address_space(3))) unsigned int*)l, 16, 0, 0);
}

// ---------------------------------------------------------------------------
// Cast: state f32 -> bf16; 5 weights -> Wcat[1280][256] bf16; biases -> f32.
// ---------------------------------------------------------------------------
__global__ __launch_bounds__(256) void cast_all(const float* __restrict__ state,
                                                const float* __restrict__ W_lk, const float* __restrict__ W_rk,
                                                const float* __restrict__ W_lv, const float* __restrict__ W_rv,
                                                const float* __restrict__ W_o,
                                                const float* __restrict__ b_lk, const float* __restrict__ b_rk,
                                                const float* __restrict__ b_lv, const float* __restrict__ b_rv,
                                                const float* __restrict__ b_o,
                                                ushort* __restrict__ state_bf,
                                                ushort* __restrict__ Wcat,
                                                float* __restrict__ bias_cat) {
    const int gid = blockIdx.x * 256 + threadIdx.x;
    const float* Ws[5] = {W_lk, W_rk, W_lv, W_rv, W_o};
    const float* bs[5] = {b_lk, b_rk, b_lv, b_rv, b_o};

    if (gid < 1280) bias_cat[gid] = bs[gid >> 8][gid & 255];

    if (gid < 524288) {
        float4 v = *(const float4*)&state[(size_t)gid * 4];
        ushort4 o = {f2b(v.x), f2b(v.y), f2b(v.z), f2b(v.w)};
        *(ushort4*)&state_bf[(size_t)gid * 4] = o;
    } else {
        int u = gid - 524288;            // 0..81919
        int row = u >> 6;                // 0..1279
        int k4 = (u & 63) * 4;
        const float* W = Ws[row >> 8];
        float4 v = *(const float4*)&W[(size_t)(row & 255) * 256 + k4];
        ushort4 o = {f2b(v.x), f2b(v.y), f2b(v.z), f2b(v.w)};
        *(ushort4*)&Wcat[(size_t)row * 256 + k4] = o;
    }
}

// ---------------------------------------------------------------------------
// bf16 MFMA GEMM. 128x128 tile, 4 waves, 4x4 16x16x32 frags.
// 4 BK=32 panels staged per phase (K=256 -> 2 phases, 4 barriers total).
// NOTE: dim3(64,NY) grid is already XCD-optimal: linear wg = bx + 64*by,
// wg%8 = bx%8 -> all NY readers of an A-tile land on ONE XCD. Left as is.
// RELAYOUT=1 (proj): scatter C into head-major P planes.
// ---------------------------------------------------------------------------
template <int BF16OUT, int RELAYOUT>
__global__ __launch_bounds__(256) void gemm_mfma(const ushort* __restrict__ A,
                                                 const ushort* __restrict__ Bw,
                                                 const float* __restrict__ bias,
                                                 void* __restrict__ Cv, int ldc) {
    __shared__ __align__(16) ushort As[4][128 * 32];
    __shared__ __align__(16) ushort Bs[4][128 * 32];
    const int tid = threadIdx.x;
    const int lane = tid & 63;
    const int wave = tid >> 6;
    const int wm = (wave & 1) * 64;
    const int wn = (wave >> 1) * 64;
    const int row0 = blockIdx.x * 128;
    const int col0 = blockIdx.y * 128;

    const int lr = lane >> 2;        // 0..15
    const int lkq = (lane & 3) * 8;  // {0,8,16,24}

    const ushort* gA0 = A + (size_t)(row0 + wave * 32 + lr) * 256 + lkq;
    const ushort* gA1 = gA0 + 16 * 256;
    const ushort* gB0 = Bw + (size_t)(col0 + wave * 32 + lr) * 256 + lkq;
    const ushort* gB1 = gB0 + 16 * 256;

    const int fr = lane & 15;
    const int fk = (lane >> 4) * 8;

    f32x4 acc[4][4] = {};

    for (int half = 0; half < 2; ++half) {
        const int k0 = half * 128;
        __syncthreads();
#pragma unroll
        for (int pp = 0; pp < 4; ++pp) {
            glds16(gA0 + k0 + pp * 32, &As[pp][(wave * 32) * 32]);
            glds16(gA1 + k0 + pp * 32, &As[pp][(wave * 32 + 16) * 32]);
            glds16(gB0 + k0 + pp * 32, &Bs[pp][(wave * 32) * 32]);
            glds16(gB1 + k0 + pp * 32, &Bs[pp][(wave * 32 + 16) * 32]);
        }
        __syncthreads();

#pragma unroll
        for (int pp = 0; pp < 4; ++pp) {
            bf16x8 af[4], bf[4];
#pragma unroll
            for (int i = 0; i < 4; ++i)
                af[i] = *(const bf16x8*)&As[pp][(wm + i * 16 + fr) * 32 + fk];
#pragma unroll
            for (int j = 0; j < 4; ++j)
                bf[j] = *(const bf16x8*)&Bs[pp][(wn + j * 16 + fr) * 32 + fk];
#pragma unroll
            for (int i = 0; i < 4; ++i)
#pragma unroll
                for (int j = 0; j < 4; ++j)
                    acc[i][j] = __builtin_amdgcn_mfma_f32_16x16x32_bf16(af[i], bf[j], acc[i][j], 0, 0, 0);
        }
    }

#pragma unroll
    for (int j = 0; j < 4; ++j) {
        const int col = col0 + wn + j * 16 + (lane & 15);
        const float bv = bias[col];
#pragma unroll
        for (int i = 0; i < 4; ++i) {
            const int rbase = row0 + wm + i * 16 + (lane >> 4) * 4;
#pragma unroll
            for (int r = 0; r < 4; ++r) {
                float o = acc[i][j][r] + bv;
                if (RELAYOUT) {
                    const int row = rbase + r;
                    const int bb = row >> 12, rr = row & 4095;
                    const int proj = col >> 8, hh = (col >> 5) & 7, dk = col & 31;
                    ((ushort*)Cv)[(size_t)proj * PROJ_ELEMS +
                                  ((size_t)(bb * 8 + hh) * 4096 + rr) * 32 + dk] = f2b(o);
                } else if (BF16OUT) {
                    ((ushort*)Cv)[(size_t)(rbase + r) * ldc + col] = f2b(o);
                } else {
                    ((float*)Cv)[(size_t)(rbase + r) * ldc + col] = o;
                }
            }
        }
    }
}

// ---------------------------------------------------------------------------
// FUSED scores + online-softmax + gated combine, v8.
// 1D grid 256 blocks, XCD-chunked: 2 heads per XCD -> per-XCD working set
// (2x1MB P + 0.25MB mask) fits the 4MB L2; scores-phase LK/RK global frag
// loads become L2 hits instead of L3 (~600cy -> ~200cy).
// Softmax diet: softmax phase computes only mnew/alpha (no p write-back,
// lstate deleted). Gate computes p = exp(s - mnew) inline (trans pipe has
// slack under the gate's LDS bound) and accumulates l in registers.
// Same 3 barriers per chunk as v7.
// ---------------------------------------------------------------------------
__global__ __launch_bounds__(512, 2) void fused_attn(const ushort* __restrict__ P,
                                                     const unsigned char* __restrict__ mask,
                                                     ushort* __restrict__ xbuf) {
    // LVb: [buf][16 x][16 a][32 dk] bf16. RVb: [buf][16 a][16 y][32 dk] bf16.
    // atts: f32 [16 a][16 x][20 y] (raw masked scores).
    __shared__ __align__(16) ushort LVb[2][16 * 512];   // 2 x 16 KB
    __shared__ __align__(16) ushort RVb[2][16 * 512];   // 2 x 16 KB
    __shared__ __align__(16) float atts[16 * 16 * 20];  // 20 KB
    __shared__ float mstate[256];
    __shared__ float alphas[256];

    // XCD-chunked decode: wg%8 = XCD (round-robin dispatch).
    const int bid = blockIdx.x;
    const int xcd = bid & 7;
    const int q = bid >> 3;            // 0..31
    const int bh = xcd * 2 + (q >> 4); // 2 heads per XCD
    const int t = q & 15;
    const int b = bh >> 3, h = bh & 7;
    const int x0 = (t & 3) * 16, y0 = (t >> 2) * 16;
    const int tid = threadIdx.x;
    const int lane = tid & 63, wave = tid >> 6;

    const size_t HB = (size_t)bh * 4096 * 32;   // head slice offset (elements)
    const ushort* PLK = P + HB;
    const ushort* PRK = P + (size_t)1 * PROJ_ELEMS + HB;
    const ushort* PLV = P + (size_t)2 * PROJ_ELEMS + HB;
    const ushort* PRV = P + (size_t)3 * PROJ_ELEMS + HB;

    // gate coords: x = wave*2 + i, y = y0 + gy, d = du*8 + 2q + {0,1}
    const int gy = lane >> 2;   // 0..15
    const int du = lane & 3;    // 0..3 (u32-quad of d)
    // softmax coords (threads 0..255): pos = sx*16+sy = tid
    const int sx = tid >> 4, sy = tid & 15;
    if (tid < 256) mstate[tid] = -3.0e38f;

    // staging lane mapping (per glds16: 16 rows x 32 dk, 16B/lane)
    const int sa = lane >> 2, soct = lane & 3;
    const int r2 = wave * 2;

    f32x2 acc[2][4] = {};
    float lacc[2] = {0.0f, 0.0f};
    const float scale = 0.17677669529663687f; // 1/sqrt(32)

#define STAGE(ac_, buf_)                                                                     \
    do {                                                                                     \
        glds16(PLV + ((size_t)(x0 + r2) * 64 + (ac_) + sa) * 32 + soct * 8,                  \
               &LVb[buf_][r2 * 512]);                                                        \
        glds16(PLV + ((size_t)(x0 + r2 + 1) * 64 + (ac_) + sa) * 32 + soct * 8,              \
               &LVb[buf_][(r2 + 1) * 512]);                                                  \
        glds16(PRV + ((size_t)((ac_) + r2) * 64 + y0 + sa) * 32 + soct * 8,                  \
               &RVb[buf_][r2 * 512]);                                                        \
        glds16(PRV + ((size_t)((ac_) + r2 + 1) * 64 + y0 + sa) * 32 + soct * 8,              \
               &RVb[buf_][(r2 + 1) * 512]);                                                  \
    } while (0)

    STAGE(0, 0);  // prologue; drained at first loop-top barrier

    for (int c = 0; c < 4; ++c) {
        const int ac = c * 16;
        const int cur = c & 1;
        __syncthreads();  // drains stage(c); protects atts (prev gate done)

        // ---- scores: direct global frags + MFMA, mask direct ----
        {
            const int fr = lane & 15, fk = (lane >> 4) * 8;
            const int yq = lane & 15, xq = (lane >> 4) * 4;
#pragma unroll
            for (int aw = 0; aw < 2; ++aw) {
                const int a = wave * 2 + aw;
                bf16x8 af = *(const bf16x8*)&PLK[((size_t)(x0 + fr) * 64 + ac + a) * 32 + fk];
                bf16x8 bf = *(const bf16x8*)&PRK[((size_t)(ac + a) * 64 + y0 + fr) * 32 + fk];
                f32x4 s = {};
                s = __builtin_amdgcn_mfma_f32_16x16x32_bf16(af, bf, s, 0, 0, 0);
#pragma unroll
                for (int rr = 0; rr < 4; ++rr) {
                    const int x = xq + rr;
                    float sv = s[rr] * scale;
                    if (mask[((size_t)(b * N + x0 + x) * N + ac + a) * N + y0 + yq]) sv = -1000.0f;
                    atts[(a * 16 + x) * 20 + yq] = sv;
                }
            }
        }
        __syncthreads();

        // ---- online max over 16-a chunk: threads 0..255 own (sx, sy) ----
        // Only mnew/alpha computed here; p = exp(s-mnew) is done in the gate.
        if (tid < 256) {
            float mc = -3.0e38f;
#pragma unroll
            for (int a = 0; a < 16; ++a) mc = fmaxf(mc, atts[(a * 16 + sx) * 20 + sy]);
            const float mold = mstate[tid];
            const float mnew = fmaxf(mold, mc);
            mstate[tid] = mnew;
            alphas[tid] = __expf(mold - mnew);
        }
        __syncthreads();

        // ---- issue next chunk's staging (hides under the gate phase) ----
        if (c < 3) STAGE(ac + 16, cur ^ 1);

        // ---- rescale (acc and running l) ----
        float mn[2];
#pragma unroll
        for (int i = 0; i < 2; ++i) {
            const int x = wave * 2 + i;
            const float av = alphas[x * 16 + gy];
            mn[i] = mstate[x * 16 + gy];
            lacc[i] *= av;
#pragma unroll
            for (int qq = 0; qq < 4; ++qq) acc[i][qq] *= av;
        }

        // ---- gate: rv = 1 contiguous b128/wave/a; lv & atts broadcast ----
        {
            const unsigned* LV32 = (const unsigned*)&LVb[cur][0];
            const unsigned* RV32 = (const unsigned*)&RVb[cur][0];
#pragma unroll
            for (int a = 0; a < 16; ++a) {
                const uint4 rvw = *(const uint4*)&RV32[a * 256 + gy * 16 + du * 4];
                const f32x2 rv0 = up2(rvw.x), rv1 = up2(rvw.y);
                const f32x2 rv2 = up2(rvw.z), rv3 = up2(rvw.w);
#pragma unroll
                for (int i = 0; i < 2; ++i) {
                    const int x = wave * 2 + i;
                    const uint4 lvw = *(const uint4*)&LV32[x * 256 + a * 16 + du * 4];
                    const float sv = atts[(a * 16 + x) * 20 + gy];
                    const float w = __expf(sv - mn[i]);
                    lacc[i] += w;
                    acc[i][0] += (up2(lvw.x) * w) * rv0;
                    acc[i][1] += (up2(lvw.y) * w) * rv1;
                    acc[i][2] += (up2(lvw.z) * w) * rv2;
                    acc[i][3] += (up2(lvw.w) * w) * rv3;
                }
            }
        }
    }

    // ---- epilogue: divide by l (in regs), one 16B store per x ----
#pragma unroll
    for (int i = 0; i < 2; ++i) {
        const int x = wave * 2 + i;
        const float il = 1.0f / lacc[i];
        ushort o[8] __attribute__((aligned(16)));
#pragma unroll
        for (int qq = 0; qq < 4; ++qq) {
            o[2 * qq]     = f2b(acc[i][qq].x * il);
            o[2 * qq + 1] = f2b(acc[i][qq].y * il);
        }
        *(uint4*)&xbuf[(((size_t)b * N + x0 + x) * N + y0 + gy) * D + h * DK + du * 8] =
            *(const uint4*)o;
    }
#undef STAGE
}

// ---------------------------------------------------------------------------
extern "C" void kernel_launch(void* const* d_in, const int* in_sizes, int n_in,
                              void* d_out, int out_size, void* d_ws, size_t ws_size,
                              hipStream_t stream) {
    const float* state = (const float*)d_in[0];
    const unsigned char* mask = (const unsigned char*)d_in[1];
    const float* W_lk = (const float*)d_in[2];
    const float* b_lk = (const float*)d_in[3];
    const float* W_rk = (const float*)d_in[4];
    const float* b_rk = (const float*)d_in[5];
    const float* W_lv = (const float*)d_in[6];
    const float* b_lv = (const float*)d_in[7];
    const float* W_rv = (const float*)d_in[8];
    const float* b_rv = (const float*)d_in[9];
    const float* W_o = (const float*)d_in[10];
    const float* b_o = (const float*)d_in[11];
    float* out = (float*)d_out;

    char* ws = (char*)d_ws;
    ushort* P_bf = (ushort*)ws;                          // 4 proj planes, 16.8 MB
    ws += (size_t)4 * PROJ_ELEMS * 2;
    float* bias_cat = (float*)ws;                        // 1280 f32
    ws += 1280 * 4;
    ushort* state_bf = (ushort*)ws;                      // 4 MB
    ws += (size_t)M * D * 2;
    ushort* Wcat = (ushort*)ws;                          // 0.65 MB
    ws += (size_t)1280 * 256 * 2;
    ushort* xbuf_bf = (ushort*)ws;                       // 4 MB

    cast_all<<<2368, 256, 0, stream>>>(state, W_lk, W_rk, W_lv, W_rv, W_o,
                                       b_lk, b_rk, b_lv, b_rv, b_o,
                                       state_bf, Wcat, bias_cat);
    gemm_mfma<1, 1><<<dim3(M / 128, 8), 256, 0, stream>>>(state_bf, Wcat, bias_cat, P_bf, 1024);
    fused_attn<<<256, 512, 0, stream>>>(P_bf, mask, xbuf_bf);
    gemm_mfma<0, 0><<<dim3(M / 128, 2), 256, 0, stream>>>(xbuf_bf, Wcat + 1024 * 256, bias_cat + 1024, out, 256);
}

// Round 4
// 120.948 us; speedup vs baseline: 1.0421x; 1.0421x over previous
//
#include <hip/hip_runtime.h>

#define B 2
#define N 64
#define D 256
#define H 8
#define DK 32
#define M (B * N * N) // 8192

typedef __attribute__((ext_vector_type(8))) short bf16x8;
typedef __attribute__((ext_vector_type(4))) float f32x4;
typedef __attribute__((ext_vector_type(2))) float f32x2;

// P is head-major: 4 proj planes of [b][h][r1*64+r2][32] bf16
#define PROJ_ELEMS (2097152)  // B*H*4096*32

__device__ __forceinline__ ushort f2b(float f) {
    union { float f; unsigned u; } v; v.f = f;
    unsigned r = v.u + 0x7fffu + ((v.u >> 16) & 1u); // RNE
    return (ushort)(r >> 16);
}
__device__ __forceinline__ float b2f(ushort u) {
    union { unsigned u; float f; } v; v.u = ((unsigned)u) << 16; return v.f;
}
// unpack 2 packed bf16 (u32) -> float2
__device__ __forceinline__ f32x2 up2(unsigned u) {
    union { unsigned u; float f; } lo, hi;
    lo.u = u << 16; hi.u = u & 0xffff0000u;
    f32x2 r; r.x = lo.f; r.y = hi.f; return r;
}

// async 16B/lane global->LDS (dst = wave-uniform base + lane*16)
__device__ __forceinline__ void glds16(const ushort* g, ushort* l) {
    __builtin_amdgcn_global_load_lds(
        (const __attribute__((address_space(1))) unsigned int*)g,
        (__attribute__((address_space(3))) unsigned int*)l, 16, 0, 0);
}

// ---------------------------------------------------------------------------
// Cast: state f32 -> bf16; 5 weights -> Wcat[1280][256] bf16; biases -> f32.
// ---------------------------------------------------------------------------
__global__ __launch_bounds__(256) void cast_all(const float* __restrict__ state,
                                                const float* __restrict__ W_lk, const float* __restrict__ W_rk,
                                                const float* __restrict__ W_lv, const float* __restrict__ W_rv,
                                                const float* __restrict__ W_o,
                                                const float* __restrict__ b_lk, const float* __restrict__ b_rk,
                                                const float* __restrict__ b_lv, const float* __restrict__ b_rv,
                                                const float* __restrict__ b_o,
                                                ushort* __restrict__ state_bf,
                                                ushort* __restrict__ Wcat,
                                                float* __restrict__ bias_cat) {
    const int gid = blockIdx.x * 256 + threadIdx.x;
    const float* Ws[5] = {W_lk, W_rk, W_lv, W_rv, W_o};
    const float* bs[5] = {b_lk, b_rk, b_lv, b_rv, b_o};

    if (gid < 1280) bias_cat[gid] = bs[gid >> 8][gid & 255];

    if (gid < 524288) {
        float4 v = *(const float4*)&state[(size_t)gid * 4];
        ushort4 o = {f2b(v.x), f2b(v.y), f2b(v.z), f2b(v.w)};
        *(ushort4*)&state_bf[(size_t)gid * 4] = o;
    } else {
        int u = gid - 524288;            // 0..81919
        int row = u >> 6;                // 0..1279
        int k4 = (u & 63) * 4;
        const float* W = Ws[row >> 8];
        float4 v = *(const float4*)&W[(size_t)(row & 255) * 256 + k4];
        ushort4 o = {f2b(v.x), f2b(v.y), f2b(v.z), f2b(v.w)};
        *(ushort4*)&Wcat[(size_t)row * 256 + k4] = o;
    }
}

// ---------------------------------------------------------------------------
// bf16 MFMA GEMM. 128x128 tile, 4 waves, 4x4 16x16x32 frags.
// 4 BK=32 panels staged per phase (K=256 -> 2 phases, 4 barriers total).
// dim3(64,NY) grid is left in natural order (measured-good L2 behavior).
// RELAYOUT=1 (proj): scatter C into head-major P planes.
// ---------------------------------------------------------------------------
template <int BF16OUT, int RELAYOUT>
__global__ __launch_bounds__(256) void gemm_mfma(const ushort* __restrict__ A,
                                                 const ushort* __restrict__ Bw,
                                                 const float* __restrict__ bias,
                                                 void* __restrict__ Cv, int ldc) {
    __shared__ __align__(16) ushort As[4][128 * 32];
    __shared__ __align__(16) ushort Bs[4][128 * 32];
    const int tid = threadIdx.x;
    const int lane = tid & 63;
    const int wave = tid >> 6;
    const int wm = (wave & 1) * 64;
    const int wn = (wave >> 1) * 64;
    const int row0 = blockIdx.x * 128;
    const int col0 = blockIdx.y * 128;

    const int lr = lane >> 2;        // 0..15
    const int lkq = (lane & 3) * 8;  // {0,8,16,24}

    const ushort* gA0 = A + (size_t)(row0 + wave * 32 + lr) * 256 + lkq;
    const ushort* gA1 = gA0 + 16 * 256;
    const ushort* gB0 = Bw + (size_t)(col0 + wave * 32 + lr) * 256 + lkq;
    const ushort* gB1 = gB0 + 16 * 256;

    const int fr = lane & 15;
    const int fk = (lane >> 4) * 8;

    f32x4 acc[4][4] = {};

    for (int half = 0; half < 2; ++half) {
        const int k0 = half * 128;
        __syncthreads();
#pragma unroll
        for (int pp = 0; pp < 4; ++pp) {
            glds16(gA0 + k0 + pp * 32, &As[pp][(wave * 32) * 32]);
            glds16(gA1 + k0 + pp * 32, &As[pp][(wave * 32 + 16) * 32]);
            glds16(gB0 + k0 + pp * 32, &Bs[pp][(wave * 32) * 32]);
            glds16(gB1 + k0 + pp * 32, &Bs[pp][(wave * 32 + 16) * 32]);
        }
        __syncthreads();

#pragma unroll
        for (int pp = 0; pp < 4; ++pp) {
            bf16x8 af[4], bf[4];
#pragma unroll
            for (int i = 0; i < 4; ++i)
                af[i] = *(const bf16x8*)&As[pp][(wm + i * 16 + fr) * 32 + fk];
#pragma unroll
            for (int j = 0; j < 4; ++j)
                bf[j] = *(const bf16x8*)&Bs[pp][(wn + j * 16 + fr) * 32 + fk];
#pragma unroll
            for (int i = 0; i < 4; ++i)
#pragma unroll
                for (int j = 0; j < 4; ++j)
                    acc[i][j] = __builtin_amdgcn_mfma_f32_16x16x32_bf16(af[i], bf[j], acc[i][j], 0, 0, 0);
        }
    }

#pragma unroll
    for (int j = 0; j < 4; ++j) {
        const int col = col0 + wn + j * 16 + (lane & 15);
        const float bv = bias[col];
#pragma unroll
        for (int i = 0; i < 4; ++i) {
            const int rbase = row0 + wm + i * 16 + (lane >> 4) * 4;
#pragma unroll
            for (int r = 0; r < 4; ++r) {
                float o = acc[i][j][r] + bv;
                if (RELAYOUT) {
                    const int row = rbase + r;
                    const int bb = row >> 12, rr = row & 4095;
                    const int proj = col >> 8, hh = (col >> 5) & 7, dk = col & 31;
                    ((ushort*)Cv)[(size_t)proj * PROJ_ELEMS +
                                  ((size_t)(bb * 8 + hh) * 4096 + rr) * 32 + dk] = f2b(o);
                } else if (BF16OUT) {
                    ((ushort*)Cv)[(size_t)(rbase + r) * ldc + col] = f2b(o);
                } else {
                    ((float*)Cv)[(size_t)(rbase + r) * ldc + col] = o;
                }
            }
        }
    }
}

// ---------------------------------------------------------------------------
// FUSED scores + online-softmax + gated combine, v9.
// = v7 structure (measured-good) with a-chunk 32 instead of 16:
//  - barriers 12 -> 6 per block; rescale passes 4 -> 2.
//  - scores phase has 4 MFMAs' loads in flight per wave (2x MLP).
//  - LV/RV single-buffered (32KB+32KB); STAGE(c) issued right after the
//    top barrier, drained at the post-scores barrier -> hides under the
//    scores phase (which never touches LV/RV LDS).
// Grid back to natural dim3(4,4,16); v8's XCD remap and exp-in-gate REVERTED
// (measured -13us regression).
// ---------------------------------------------------------------------------
__global__ __launch_bounds__(512, 2) void fused_attn(const ushort* __restrict__ P,
                                                     const unsigned char* __restrict__ mask,
                                                     ushort* __restrict__ xbuf) {
    // LVb: [16 x][32 a][32 dk] bf16 (32KB). RVb: [32 a][16 y][32 dk] bf16 (32KB).
    // atts: f32 [32 a][16 x][20 y] (40KB).
    __shared__ __align__(16) ushort LVb[16 * 1024];
    __shared__ __align__(16) ushort RVb[32 * 512];
    __shared__ __align__(16) float atts[32 * 16 * 20];
    __shared__ float mstate[16 * 20];
    __shared__ float lstate[16 * 20];
    __shared__ float alphas[16 * 20];

    const int bh = blockIdx.z;
    const int b = bh >> 3, h = bh & 7;
    const int x0 = blockIdx.x * 16, y0 = blockIdx.y * 16;
    const int tid = threadIdx.x;
    const int lane = tid & 63, wave = tid >> 6;

    const size_t HB = (size_t)bh * 4096 * 32;   // head slice offset (elements)
    const ushort* PLK = P + HB;
    const ushort* PRK = P + (size_t)1 * PROJ_ELEMS + HB;
    const ushort* PLV = P + (size_t)2 * PROJ_ELEMS + HB;
    const ushort* PRV = P + (size_t)3 * PROJ_ELEMS + HB;

    // gate coords: x = wave*2 + i, y = y0 + gy, d = du*8 + ...
    const int gy = lane >> 2;   // 0..15
    const int du = lane & 3;    // 0..3 (u32-quad of d)
    // softmax coords (threads 0..255)
    const int sx = tid >> 4, sy = tid & 15;
    if (tid < 256) {
        mstate[sx * 20 + sy] = -3.0e38f;
        lstate[sx * 20 + sy] = 0.0f;
    }

    // staging lane mapping (per glds16: 16 rows x 32 dk, 16B/lane)
    const int sa = lane >> 2, soct = lane & 3;
    const int r2 = wave * 2;     // LV x-rows owned by this wave
    const int a4 = wave * 4;     // RV a-rows owned by this wave

    f32x2 acc[2][4] = {};
    float lacc_unused = 0.0f; (void)lacc_unused;
    const float scale = 0.17677669529663687f; // 1/sqrt(32)

    for (int c = 0; c < 2; ++c) {
        const int ac = c * 32;
        __syncthreads();  // gate(c-1) done (LV/RV free); atts free

        // ---- issue STAGE(c): 8 glds16/wave; drains at post-scores barrier ----
        // LV: 2 x-rows, each 32a x 32dk = 2 glds16 (a-halves)
        glds16(PLV + ((size_t)(x0 + r2) * 64 + ac + sa) * 32 + soct * 8,
               &LVb[r2 * 1024]);
        glds16(PLV + ((size_t)(x0 + r2) * 64 + ac + 16 + sa) * 32 + soct * 8,
               &LVb[r2 * 1024 + 512]);
        glds16(PLV + ((size_t)(x0 + r2 + 1) * 64 + ac + sa) * 32 + soct * 8,
               &LVb[(r2 + 1) * 1024]);
        glds16(PLV + ((size_t)(x0 + r2 + 1) * 64 + ac + 16 + sa) * 32 + soct * 8,
               &LVb[(r2 + 1) * 1024 + 512]);
        // RV: 4 a-rows, each 16y x 32dk = 1 glds16
#pragma unroll
        for (int k = 0; k < 4; ++k)
            glds16(PRV + ((size_t)(ac + a4 + k) * 64 + y0 + sa) * 32 + soct * 8,
                   &RVb[(a4 + k) * 512]);

        // ---- scores: direct global frags + MFMA, mask direct (4 a per wave) ----
        {
            const int fr = lane & 15, fk = (lane >> 4) * 8;
            const int yq = lane & 15, xq = (lane >> 4) * 4;
#pragma unroll
            for (int aw = 0; aw < 4; ++aw) {
                const int a = wave * 4 + aw;
                bf16x8 af = *(const bf16x8*)&PLK[((size_t)(x0 + fr) * 64 + ac + a) * 32 + fk];
                bf16x8 bf = *(const bf16x8*)&PRK[((size_t)(ac + a) * 64 + y0 + fr) * 32 + fk];
                f32x4 s = {};
                s = __builtin_amdgcn_mfma_f32_16x16x32_bf16(af, bf, s, 0, 0, 0);
#pragma unroll
                for (int rr = 0; rr < 4; ++rr) {
                    const int x = xq + rr;
                    float sv = s[rr] * scale;
                    if (mask[((size_t)(b * N + x0 + x) * N + ac + a) * N + y0 + yq]) sv = -1000.0f;
                    atts[(a * 16 + x) * 20 + yq] = sv;
                }
            }
        }
        __syncthreads();  // scores visible; STAGE(c) drained (vmcnt0)

        // ---- online softmax over 32-a chunk: threads 0..255 own (sx, sy) ----
        if (tid < 256) {
            float mc = -3.0e38f;
#pragma unroll
            for (int a = 0; a < 32; ++a) mc = fmaxf(mc, atts[(a * 16 + sx) * 20 + sy]);
            const float mold = mstate[sx * 20 + sy];
            const float mnew = fmaxf(mold, mc);
            const float alpha = __expf(mold - mnew);
            float ps = 0.0f;
#pragma unroll
            for (int a = 0; a < 32; ++a) {
                float p = __expf(atts[(a * 16 + sx) * 20 + sy] - mnew);
                atts[(a * 16 + sx) * 20 + sy] = p;
                ps += p;
            }
            lstate[sx * 20 + sy] = lstate[sx * 20 + sy] * alpha + ps;
            mstate[sx * 20 + sy] = mnew;
            alphas[sx * 20 + sy] = alpha;
        }
        __syncthreads();

        // ---- rescale ----
#pragma unroll
        for (int i = 0; i < 2; ++i) {
            const float av = alphas[(wave * 2 + i) * 20 + gy];
#pragma unroll
            for (int q = 0; q < 4; ++q) acc[i][q] *= av;
        }

        // ---- gate: rv = 1 contiguous b128/wave/a; lv & atts broadcast ----
        {
            const unsigned* LV32 = (const unsigned*)LVb;
            const unsigned* RV32 = (const unsigned*)RVb;
#pragma unroll
            for (int a = 0; a < 32; ++a) {
                const uint4 rvw = *(const uint4*)&RV32[a * 256 + gy * 16 + du * 4];
                const f32x2 rv0 = up2(rvw.x), rv1 = up2(rvw.y);
                const f32x2 rv2 = up2(rvw.z), rv3 = up2(rvw.w);
#pragma unroll
                for (int i = 0; i < 2; ++i) {
                    const int x = wave * 2 + i;
                    const uint4 lvw = *(const uint4*)&LV32[x * 512 + a * 16 + du * 4];
                    const float w = atts[(a * 16 + x) * 20 + gy];
                    acc[i][0] += (up2(lvw.x) * w) * rv0;
                    acc[i][1] += (up2(lvw.y) * w) * rv1;
                    acc[i][2] += (up2(lvw.z) * w) * rv2;
                    acc[i][3] += (up2(lvw.w) * w) * rv3;
                }
            }
        }
    }

    // ---- epilogue: divide by l, one 16B store per x ----
#pragma unroll
    for (int i = 0; i < 2; ++i) {
        const int x = wave * 2 + i;
        const float il = 1.0f / lstate[x * 20 + gy];
        ushort o[8] __attribute__((aligned(16)));
#pragma unroll
        for (int q = 0; q < 4; ++q) {
            o[2 * q]     = f2b(acc[i][q].x * il);
            o[2 * q + 1] = f2b(acc[i][q].y * il);
        }
        *(uint4*)&xbuf[(((size_t)b * N + x0 + x) * N + y0 + gy) * D + h * DK + du * 8] =
            *(const uint4*)o;
    }
}

// ---------------------------------------------------------------------------
extern "C" void kernel_launch(void* const* d_in, const int* in_sizes, int n_in,
                              void* d_out, int out_size, void* d_ws, size_t ws_size,
                              hipStream_t stream) {
    const float* state = (const float*)d_in[0];
    const unsigned char* mask = (const unsigned char*)d_in[1];
    const float* W_lk = (const float*)d_in[2];
    const float* b_lk = (const float*)d_in[3];
    const float* W_rk = (const float*)d_in[4];
    const float* b_rk = (const float*)d_in[5];
    const float* W_lv = (const float*)d_in[6];
    const float* b_lv = (const float*)d_in[7];
    const float* W_rv = (const float*)d_in[8];
    const float* b_rv = (const float*)d_in[9];
    const float* W_o = (const float*)d_in[10];
    const float* b_o = (const float*)d_in[11];
    float* out = (float*)d_out;

    char* ws = (char*)d_ws;
    ushort* P_bf = (ushort*)ws;                          // 4 proj planes, 16.8 MB
    ws += (size_t)4 * PROJ_ELEMS * 2;
    float* bias_cat = (float*)ws;                        // 1280 f32
    ws += 1280 * 4;
    ushort* state_bf = (ushort*)ws;                      // 4 MB
    ws += (size_t)M * D * 2;
    ushort* Wcat = (ushort*)ws;                          // 0.65 MB
    ws += (size_t)1280 * 256 * 2;
    ushort* xbuf_bf = (ushort*)ws;                       // 4 MB

    cast_all<<<2368, 256, 0, stream>>>(state, W_lk, W_rk, W_lv, W_rv, W_o,
                                       b_lk, b_rk, b_lv, b_rv, b_o,
                                       state_bf, Wcat, bias_cat);
    gemm_mfma<1, 1><<<dim3(M / 128, 8), 256, 0, stream>>>(state_bf, Wcat, bias_cat, P_bf, 1024);
    fused_attn<<<dim3(4, 4, B * H), 512, 0, stream>>>(P_bf, mask, xbuf_bf);
    gemm_mfma<0, 0><<<dim3(M / 128, 2), 256, 0, stream>>>(xbuf_bf, Wcat + 1024 * 256, bias_cat + 1024, out, 256);
}